// Round 1
// baseline (444.872 us; speedup 1.0000x reference)
//
#include <hip/hip_runtime.h>
#include <hip/hip_bf16.h>

typedef __attribute__((ext_vector_type(8))) short  short8;   // 8 x bf16 bits = 4 VGPR
typedef __attribute__((ext_vector_type(4))) short  short4v;  // 8-byte LDS store
typedef __attribute__((ext_vector_type(4))) float  float4v;  // MFMA C/D + global float4

#define E_TILE 64
#define LDA    264   // 256 + 8 bf16 pad (breaks 512B stride)
#define LDH    136   // 128 + 8 pad

// fp32 -> bf16 bits, round-to-nearest-even
__device__ __forceinline__ short f2bf(float f) {
    union { float f; unsigned u; } v; v.f = f;
    unsigned r = (v.u + 0x7FFFu + ((v.u >> 16) & 1u)) >> 16;
    return (short)r;
}

__global__ __launch_bounds__(256, 2)
void edge_mlp_kernel(const float* __restrict__ x,
                     const int*   __restrict__ ei,
                     const float* __restrict__ W1,
                     const float* __restrict__ b1,
                     const float* __restrict__ W2,
                     const float* __restrict__ b2,
                     float*       __restrict__ out,
                     int E) {
    __shared__ short sA[E_TILE * LDA];   // gathered [src||dst] tile, bf16
    __shared__ short sH[E_TILE * LDH];   // hidden tile, bf16
    __shared__ int   sIdx[2 * E_TILE];

    const int tid  = threadIdx.x;
    const int wave = tid >> 6;
    const int lane = tid & 63;
    const int quad = lane >> 4;
    const int l16  = lane & 15;
    const long eBase = (long)blockIdx.x * E_TILE;
    const int nBase = wave * 32;         // each wave owns N-slice [nBase, nBase+32)

    // ---- stage edge indices ----
    if (tid < E_TILE) {
        long eg = eBase + tid;
        int s = 0, d = 0;
        if (eg < (long)E) { s = ei[eg]; d = ei[(long)E + eg]; }
        sIdx[tid] = s;
        sIdx[E_TILE + tid] = d;
    }

    // ---- preload weight B-fragments into registers (once per block) ----
    // B layout for mfma_16x16x32: lane holds B[k = quad*8+j][n = lane&15]
    short8 bw1[8][2];   // K1=256 -> 8 k-steps of 32; 2 n-tiles of 16
    short8 bw2[4][2];   // K2=128 -> 4 k-steps
    #pragma unroll
    for (int kt = 0; kt < 8; ++kt)
        #pragma unroll
        for (int nt = 0; nt < 2; ++nt) {
            short8 f;
            #pragma unroll
            for (int j = 0; j < 8; ++j) {
                int k = kt * 32 + quad * 8 + j;
                int n = nBase + nt * 16 + l16;
                f[j] = f2bf(W1[k * 128 + n]);
            }
            bw1[kt][nt] = f;
        }
    #pragma unroll
    for (int kt = 0; kt < 4; ++kt)
        #pragma unroll
        for (int nt = 0; nt < 2; ++nt) {
            short8 f;
            #pragma unroll
            for (int j = 0; j < 8; ++j) {
                int k = kt * 32 + quad * 8 + j;
                int n = nBase + nt * 16 + l16;
                f[j] = f2bf(W2[k * 128 + n]);
            }
            bw2[kt][nt] = f;
        }
    float b1v[2], b2v[2];
    #pragma unroll
    for (int nt = 0; nt < 2; ++nt) {
        b1v[nt] = b1[nBase + nt * 16 + l16];
        b2v[nt] = b2[nBase + nt * 16 + l16];
    }

    __syncthreads();   // sIdx visible

    // ---- gather A tile: 64 edges x 256 fp32 -> bf16 LDS ----
    // 4096 float4 loads; 256 threads x 16 iters, coalesced over features
    #pragma unroll
    for (int i = 0; i < 16; ++i) {
        int f = tid + 256 * i;     // float4 index in [0,4096)
        int e = f >> 6;            // 64 float4 per 256-float row
        int c = f & 63;
        int node = (c < 32) ? sIdx[e] : sIdx[E_TILE + e];
        int cc = c & 31;           // float4 within the node's 128-f row
        float4v v = *(const float4v*)&x[(long)node * 128 + cc * 4];
        short4v s;
        s.x = f2bf(v.x); s.y = f2bf(v.y); s.z = f2bf(v.z); s.w = f2bf(v.w);
        *(short4v*)&sA[e * LDA + c * 4] = s;
    }

    __syncthreads();   // sA visible

    // ---- GEMM1: H = relu(A @ W1 + b1), per-wave M=64 x N=32 ----
    float4v acc[4][2];
    #pragma unroll
    for (int mt = 0; mt < 4; ++mt)
        #pragma unroll
        for (int nt = 0; nt < 2; ++nt)
            acc[mt][nt] = (float4v)(0.0f);

    #pragma unroll
    for (int kt = 0; kt < 8; ++kt) {
        short8 a[4];
        #pragma unroll
        for (int mt = 0; mt < 4; ++mt)
            a[mt] = *(const short8*)&sA[(mt * 16 + l16) * LDA + kt * 32 + quad * 8];
        #pragma unroll
        for (int mt = 0; mt < 4; ++mt)
            #pragma unroll
            for (int nt = 0; nt < 2; ++nt)
                acc[mt][nt] = __builtin_amdgcn_mfma_f32_16x16x32_bf16(
                    a[mt], bw1[kt][nt], acc[mt][nt], 0, 0, 0);
    }

    // C/D layout: col = lane&15, row = quad*4 + r
    #pragma unroll
    for (int mt = 0; mt < 4; ++mt)
        #pragma unroll
        for (int nt = 0; nt < 2; ++nt)
            #pragma unroll
            for (int r = 0; r < 4; ++r) {
                int m = mt * 16 + quad * 4 + r;
                int n = nBase + nt * 16 + l16;
                float h = acc[mt][nt][r] + b1v[nt];
                h = fmaxf(h, 0.0f);
                sH[m * LDH + n] = f2bf(h);
            }

    __syncthreads();   // sH visible

    // ---- GEMM2: OUT = H @ W2 + b2 ----
    float4v acc2[4][2];
    #pragma unroll
    for (int mt = 0; mt < 4; ++mt)
        #pragma unroll
        for (int nt = 0; nt < 2; ++nt)
            acc2[mt][nt] = (float4v)(0.0f);

    #pragma unroll
    for (int kt = 0; kt < 4; ++kt) {
        short8 a[4];
        #pragma unroll
        for (int mt = 0; mt < 4; ++mt)
            a[mt] = *(const short8*)&sH[(mt * 16 + l16) * LDH + kt * 32 + quad * 8];
        #pragma unroll
        for (int mt = 0; mt < 4; ++mt)
            #pragma unroll
            for (int nt = 0; nt < 2; ++nt)
                acc2[mt][nt] = __builtin_amdgcn_mfma_f32_16x16x32_bf16(
                    a[mt], bw2[kt][nt], acc2[mt][nt], 0, 0, 0);
    }

    // ---- epilogue: fp32 stores ----
    #pragma unroll
    for (int mt = 0; mt < 4; ++mt)
        #pragma unroll
        for (int nt = 0; nt < 2; ++nt)
            #pragma unroll
            for (int r = 0; r < 4; ++r) {
                int m = mt * 16 + quad * 4 + r;
                long e = eBase + m;
                if (e < (long)E) {
                    int n = nBase + nt * 16 + l16;
                    out[e * 128 + n] = acc2[mt][nt][r] + b2v[nt];
                }
            }
}

extern "C" void kernel_launch(void* const* d_in, const int* in_sizes, int n_in,
                              void* d_out, int out_size, void* d_ws, size_t ws_size,
                              hipStream_t stream) {
    const float* x  = (const float*)d_in[0];
    const int*   ei = (const int*)d_in[1];
    const float* W1 = (const float*)d_in[2];
    const float* b1 = (const float*)d_in[3];
    const float* W2 = (const float*)d_in[4];
    const float* b2 = (const float*)d_in[5];
    float* out = (float*)d_out;
    int E = in_sizes[1] / 2;                 // edge_index is [2, E]
    int grid = (E + E_TILE - 1) / E_TILE;    // 600000/64 = 9375
    edge_mlp_kernel<<<grid, 256, 0, stream>>>(x, ei, W1, b1, W2, b2, out, E);
}